// Round 13
// baseline (236.292 us; speedup 1.0000x reference)
//
#include <hip/hip_runtime.h>
#include <cstdint>
#include <cstddef>

// Problem constants (B,S,D,H) = (2, 2048, 256, 8)
#define S_LEN 2048
#define DIM   256
#define NH    8
#define NB    2
#define HDIM  (NH * DIM)   // 2048

using bf16 = __bf16;
typedef __bf16 bf16x8 __attribute__((ext_vector_type(8)));
typedef __bf16 bf16x4 __attribute__((ext_vector_type(4)));
typedef float  f32x4  __attribute__((ext_vector_type(4)));
typedef float  f32x16 __attribute__((ext_vector_type(16)));

typedef const __attribute__((address_space(1))) unsigned int* as1_u32p;
typedef __attribute__((address_space(3))) unsigned int* as3_u32p;

// async 16B global -> LDS (no VGPR round-trip). LDS dest = wave-uniform base
// + lane*16 (m104/m108).
__device__ __forceinline__ void cp16(const bf16* g, bf16* l) {
    __builtin_amdgcn_global_load_lds((as1_u32p)g, (as3_u32p)l, 16, 0, 0);
}

// ---------------------------------------------------------------------------
// Fused prep (one launch): z=0..2 -> wQ/wK/wV transpose-cast (h = y>>2),
// z=3 -> wO transpose-cast, z=4 -> X fp32->bf16 cast. grid dim3(4,32,5).
// ---------------------------------------------------------------------------
__global__ __launch_bounds__(256) void prep_kernel(const float* __restrict__ X,
                                                   const float* __restrict__ wQ,
                                                   const float* __restrict__ wK,
                                                   const float* __restrict__ wV,
                                                   const float* __restrict__ wO,
                                                   bf16* __restrict__ Xb,
                                                   bf16* __restrict__ WQt,
                                                   bf16* __restrict__ WKt,
                                                   bf16* __restrict__ WVt,
                                                   bf16* __restrict__ WOt)
{
    const int z = blockIdx.z;
    if (z == 4) {                     // cast X
        const int t = (blockIdx.y*4 + blockIdx.x)*256 + threadIdx.x;   // 0..32767
        #pragma unroll
        for (int p = 0; p < 8; ++p) {
            const int i = (t + p*32768)*4;
            float4 v = *(const float4*)(X + i);
            bf16x4 o;
            o[0] = (bf16)v.x; o[1] = (bf16)v.y; o[2] = (bf16)v.z; o[3] = (bf16)v.w;
            *(bf16x4*)(Xb + i) = o;
        }
        return;
    }
    __shared__ float tile[64][65];
    const float* in; bf16* out; int R, C, r0, c0;
    if (z < 3) {
        const int h = blockIdx.y >> 2;
        in  = (z == 0 ? wQ : z == 1 ? wK : wV) + (size_t)h * DIM * DIM;
        out = (z == 0 ? WQt : z == 1 ? WKt : WVt) + (size_t)h * DIM * DIM;
        R = DIM; C = DIM; r0 = (blockIdx.y & 3) * 64; c0 = blockIdx.x * 64;
    } else {
        in = wO; out = WOt; R = HDIM; C = DIM;
        r0 = blockIdx.y * 64; c0 = blockIdx.x * 64;
    }
    const int tr  = threadIdx.x >> 4;
    const int tc4 = (threadIdx.x & 15) * 4;
    #pragma unroll
    for (int p = 0; p < 4; ++p) {
        int row = p * 16 + tr;
        float4 v = *(const float4*)(in + (size_t)(r0 + row) * C + c0 + tc4);
        tile[row][tc4+0] = v.x; tile[row][tc4+1] = v.y;
        tile[row][tc4+2] = v.z; tile[row][tc4+3] = v.w;
    }
    __syncthreads();
    #pragma unroll
    for (int p = 0; p < 4; ++p) {
        int orow = p * 16 + tr;
        bf16x4 o;
        #pragma unroll
        for (int j = 0; j < 4; ++j) o[j] = (bf16)tile[tc4 + j][orow];
        *(bf16x4*)(out + (size_t)(c0 + orow) * R + r0 + tc4) = o;
    }
}

// ---------------------------------------------------------------------------
// 128x128-tile bf16 MFMA GEMM, ROUND-8-verified (async-DMA, XOR swizzle,
// single barrier per k-step). EPI: 0 bf16, 1 f32, 2 f32 atomicAdd.
// ---------------------------------------------------------------------------
template<int EPI>
__device__ __forceinline__ void gemm_tile(const bf16* __restrict__ A, const bf16* __restrict__ BT,
                                          void* __restrict__ C, bf16* As, bf16* Bs,
                                          int tm, int tn, int K, int lda, int ldb, int ldc)
{
    const int tid  = threadIdx.x;
    const int lane = tid & 63;
    const int wave = tid >> 6;
    const int wm   = (wave >> 1) << 6;
    const int wn   = (wave & 1) << 6;
    const int l16  = lane & 15;
    const int quad = lane >> 4;

    const int m0 = tm << 7, n0 = tn << 7;

    const int srow = (lane >> 2);
    const int gch  = (lane & 3) ^ (srow & 3);

    f32x4 acc[4][4] = {};

    const int ksteps = K >> 5;

    #pragma unroll
    for (int j = 0; j < 2; ++j) {
        const int g = wave*2 + j;
        cp16(A  + (size_t)(m0 + g*16 + srow)*lda + (gch << 3), As + g*512);
        cp16(BT + (size_t)(n0 + g*16 + srow)*ldb + (gch << 3), Bs + g*512);
    }

    for (int ks = 0; ks < ksteps; ++ks) {
        const int pb = ks & 1;
        asm volatile("s_waitcnt vmcnt(0)" ::: "memory");
        __syncthreads();
        if (ks + 1 < ksteps) {
            const int k1 = (ks + 1) << 5;
            #pragma unroll
            for (int j = 0; j < 2; ++j) {
                const int g = wave*2 + j;
                cp16(A  + (size_t)(m0 + g*16 + srow)*lda + k1 + (gch << 3),
                     As + (pb ^ 1)*4096 + g*512);
                cp16(BT + (size_t)(n0 + g*16 + srow)*ldb + k1 + (gch << 3),
                     Bs + (pb ^ 1)*4096 + g*512);
            }
        }
        const bf16* Ab = As + pb*4096;
        const bf16* Bb = Bs + pb*4096;
        bf16x8 af[4], bfv[4];
        #pragma unroll
        for (int i = 0; i < 4; ++i) {
            const int row = wm + i*16 + l16;
            af[i]  = *(const bf16x8*)(Ab + row*32 + ((quad ^ (l16 & 3)) << 3));
        }
        #pragma unroll
        for (int i = 0; i < 4; ++i) {
            const int row = wn + i*16 + l16;
            bfv[i] = *(const bf16x8*)(Bb + row*32 + ((quad ^ (l16 & 3)) << 3));
        }
        #pragma unroll
        for (int i = 0; i < 4; ++i)
            #pragma unroll
            for (int j = 0; j < 4; ++j)
                acc[i][j] = __builtin_amdgcn_mfma_f32_16x16x32_bf16(af[i], bfv[j], acc[i][j], 0, 0, 0);
    }

    #pragma unroll
    for (int i = 0; i < 4; ++i)
        #pragma unroll
        for (int j = 0; j < 4; ++j)
            #pragma unroll
            for (int r = 0; r < 4; ++r) {
                int mg = m0 + wm + i*16 + quad*4 + r;
                int ng = n0 + wn + j*16 + l16;
                float v = acc[i][j][r];
                if (EPI == 0)      ((bf16*)C)[(size_t)mg * ldc + ng] = (bf16)v;
                else if (EPI == 1) ((float*)C)[(size_t)mg * ldc + ng] = v;
                else               atomicAdd(&((float*)C)[(size_t)mg * ldc + ng], v);
            }
}

// QKV projections. grid = (32 tiles, 48 = {Q,K,V} x b x h). LDS 32 KB.
__global__ __launch_bounds__(256) void proj_kernel(const bf16* __restrict__ Xb,
    const bf16* __restrict__ WQt, const bf16* __restrict__ WKt, const bf16* __restrict__ WVt,
    bf16* __restrict__ Qg, bf16* __restrict__ Kg, bf16* __restrict__ VTg)
{
    __shared__ __align__(16) bf16 smem[4 * 4096];
    const int by  = blockIdx.y;
    const int mat = by >> 4;
    const int b   = (by >> 3) & 1;
    const int h   = by & 7;
    const int bx  = blockIdx.x;
    const bf16*  Xbb = Xb + (size_t)b * S_LEN * DIM;
    const size_t bh  = (size_t)(b * NH + h);
    if (mat == 0) {
        gemm_tile<0>(Xbb, WQt + (size_t)h*DIM*DIM, Qg + bh*S_LEN*DIM, smem, smem + 8192,
                     bx & 15, bx >> 4, DIM, DIM, DIM, DIM);
    } else if (mat == 1) {
        gemm_tile<0>(Xbb, WKt + (size_t)h*DIM*DIM, Kg + bh*S_LEN*DIM, smem, smem + 8192,
                     bx & 15, bx >> 4, DIM, DIM, DIM, DIM);
    } else {
        gemm_tile<0>(WVt + (size_t)h*DIM*DIM, Xbb, VTg + bh*DIM*S_LEN, smem, smem + 8192,
                     bx & 1, bx >> 1, DIM, DIM, DIM, S_LEN);
    }
}

// out[4096,256] += Ret[4096,2048(k-slice)] @ WOt^T, K-split x4. out pre-zeroed.
__global__ __launch_bounds__(256) void outproj_kernel(const bf16* __restrict__ Ret,
                                                      const bf16* __restrict__ WOt,
                                                      float* __restrict__ out)
{
    __shared__ __align__(16) bf16 smem[4 * 4096];
    int bx = blockIdx.x;
    int t  = bx & 63;
    int kq = bx >> 6;
    gemm_tile<2>(Ret + kq*512, WOt + kq*512, out, smem, smem + 8192,
                 t >> 1, t & 1, 512, HDIM, HDIM, DIM);
}

// ---------------------------------------------------------------------------
// Split-K flash causal attention (round 13): 32x32x16 MFMA, 64-key steps.
// Rationale: 4 neutral rounds at ~70us share one invariant -- ~164 KB of LDS
// traffic per 32-key step (B-operand economy of 16x16x32 = 16 FLOP/LDS-byte).
// 32x32x16 gives 64 FLOP/LDS-byte: per-64-key traffic 328 KB -> 136 KB.
//   QK: wave (rh=w>>1, kh=w&1) computes S[rh*32..+32][kh*32..+32], 16-chain.
//   PV: wave covers rows rh*32..+32 x cols (w&1)*128..+128 (4 32x32 tiles).
// C/D layout (HW-verified m74/m101): col=lane&31, row=(reg&3)+8*(reg>>2)+4*(lane>>5).
// A/B layout (K-doubling analogy): m=lane&31, k=(lane>>5)*8+j.
// Single-buffered K+V (74.7 KB -> 2 blocks/CU); K(t+1) issued after mid
// barrier (PV never reads Ks); V(t) waited via vmcnt(8) (K stays oldest).
// Uniform-length partition + longest-first order (R12), steps now 64-key.
// ---------------------------------------------------------------------------
__global__ __launch_bounds__(256, 2) void attn_kernel(const bf16* __restrict__ Qg,
                                                      const bf16* __restrict__ Kg,
                                                      const bf16* __restrict__ VTg,
                                                      bf16* __restrict__ Ret,
                                                      bf16* __restrict__ Opart,
                                                      float* __restrict__ Lpart)
{
    __shared__ __align__(16) bf16 Ks [64 * 256];   // 32 KB, swizzle c^(row&31)
    __shared__ __align__(16) bf16 VTs[256 * 64];   // 32 KB, swizzle c^(e&7)
    __shared__ __align__(16) bf16 Ps [64 * 72];    // 9 KB, padded

    // dispatch-slot -> bid, sorted by 64-key block length descending
    static const unsigned char order[63] = {
        10,29,31,32,57,60,61,
        9,25,27,28,30,48,51,52,54,55,56,58,59,62,
        8,21,23,24,26,39,42,43,45,46,47,49,50,53,
        7,17,19,20,22,33,34,36,37,38,40,41,44,
        6,13,15,16,18,35,
        5,11,12,14,
        4,3,2,1,0 };

    const int tid  = threadIdx.x;
    const int lane = tid & 63;
    const int wave = tid >> 6;
    const int l32  = lane & 31;
    const int half = lane >> 5;            // 0|1
    const int rh   = wave >> 1;            // row-half (QK and PV)
    const int kh   = wave & 1;             // QK key-half
    const int cw   = (wave & 1) * 128;     // PV col base

    // ---- uniform-length work mapping (R12 structure, 64-key steps) ----
    const int bx  = blockIdx.x;                      // 0..1007
    const int bh  = bx & 15;
    const int bid = order[bx >> 4];                  // 0..62
    int qt, s, nsp;
    if (bid <= 10)      { qt = bid;                    s = 0;       nsp = 1; }
    else if (bid <= 32) { int k = bid - 11; qt = 11 + (k >> 1); s = k & 1; nsp = 2; }
    else                { int k = bid - 33; int q3 = k / 3; qt = 22 + q3; s = k - 3*q3; nsp = 3; }
    const int b = bh >> 3, h = bh & 7;

    const int S2 = qt + 1;                 // total 64-key steps for this q-tile
    const int base = S2 / nsp, rem = S2 - nsp*base;
    const int kstep0 = s*base + (s < rem ? s : rem);
    const int kstep1 = kstep0 + base + (s < rem ? 1 : 0);

    const bf16* Qbh  = Qg  + (size_t)(b*NH + h) * S_LEN * DIM;
    const bf16* Kbh  = Kg  + (size_t)(b*NH + h) * S_LEN * DIM;
    const bf16* VTbh = VTg + (size_t)(b*NH + h) * DIM * S_LEN;

    const int qbase32 = qt*64 + rh*32;     // this wave's 32 Q rows

    // Preload Q rows as 16 A-frags (32 rows x K=256; 8 bf16/lane per frag)
    bf16x8 qf[16];
    #pragma unroll
    for (int kc = 0; kc < 16; ++kc)
        qf[kc] = *(const bf16x8*)(Qbh + (size_t)(qbase32 + l32)*DIM + kc*16 + half*8);

    f32x16 o[4] = {};                      // 32 rows x 128 cols (4 32x32 C-tiles)
    float l_part[16] = {};

    // prologue: issue K(kstep0) DMA (8 per wave; rows wave*16..+16)
    {
        const int t00 = kstep0 << 6;
        #pragma unroll
        for (int j = 0; j < 8; ++j) {
            const int sN = ((wave*8 + j) << 6) + lane;   // 0..2047
            const int ts = sN >> 5, cs = sN & 31;
            cp16(Kbh + (size_t)(t00 + ts)*DIM + ((cs ^ (ts & 31)) << 3),
                 Ks + ((wave*8 + j) << 9));
        }
    }

    for (int step = kstep0; step < kstep1; ++step) {
        const int t0 = step << 6;
        // (A) all prev-step PV reads of VTs/Ps done (raw barrier: do NOT
        // drain the in-flight K DMA)
        asm volatile("s_barrier" ::: "memory");
        // issue V(t) DMA (8 per wave)
        #pragma unroll
        for (int j = 0; j < 8; ++j) {
            const int sN = ((wave*8 + j) << 6) + lane;   // 0..2047
            const int es = sN >> 3, cs = sN & 7;
            cp16(VTbh + (size_t)es*S_LEN + t0 + ((cs ^ (es & 7)) << 3),
                 VTs + ((wave*8 + j) << 9));
        }
        // (B) wait K(t) only (8 newest = V stay outstanding); align waves
        asm volatile("s_waitcnt vmcnt(8)\n\ts_barrier" ::: "memory");

        // QK: S = Q K^T for 32 rows x 32 keys, 16-chained 32x32x16
        f32x16 sacc = {};
        #pragma unroll
        for (int kc = 0; kc < 16; ++kc) {
            const int g = kc*2 + half;     // 16B chunk within key row
            bf16x8 kf = *(const bf16x8*)(Ks + (size_t)(kh*32 + l32)*256 + ((g ^ l32) << 3));
            sacc = __builtin_amdgcn_mfma_f32_32x32x16_bf16(qf[kc], kf, sacc, 0, 0, 0);
        }

        // softmax (no-max): p = exp(s/16) masked; write P to Ps [64][72]
        const int tg = t0 + kh*32 + l32;
        #pragma unroll
        for (int r = 0; r < 16; ++r) {
            const int lrow = rh*32 + 4*half + (r & 3) + 8*(r >> 2);
            const int qgi  = qt*64 + lrow;
            float p = (tg <= qgi) ? __expf(sacc[r] * 0.0625f) : 0.0f;
            l_part[r] += p;
            Ps[lrow*72 + kh*32 + l32] = (bf16)p;
        }

        // (C) Ps visible; all QK reads of Ks done (implicit vmcnt(0) drains V)
        __syncthreads();

        // issue K(t+1) into Ks (safe: PV never reads Ks)
        if (step + 1 < kstep1) {
            const int t1 = (step + 1) << 6;
            #pragma unroll
            for (int j = 0; j < 8; ++j) {
                const int sN = ((wave*8 + j) << 6) + lane;
                const int ts = sN >> 5, cs = sN & 31;
                cp16(Kbh + (size_t)(t1 + ts)*DIM + ((cs ^ (ts & 31)) << 3),
                     Ks + ((wave*8 + j) << 9));
            }
        }

        // PV: rows rh*32..+32 x cols cw..cw+128; P A-frags cached in regs
        bf16x8 pf[4];
        #pragma unroll
        for (int kc = 0; kc < 4; ++kc)
            pf[kc] = *(const bf16x8*)(Ps + (rh*32 + l32)*72 + kc*16 + half*8);
        #pragma unroll
        for (int ct = 0; ct < 4; ++ct) {
            f32x16 acc = o[ct];
            #pragma unroll
            for (int kc = 0; kc < 4; ++kc) {
                const int e = cw + ct*32 + l32;
                const int g = kc*2 + half;
                bf16x8 vf = *(const bf16x8*)(VTs + (size_t)e*64 + ((g ^ (e & 7)) << 3));
                acc = __builtin_amdgcn_mfma_f32_32x32x16_bf16(pf[kc], vf, acc, 0, 0, 0);
            }
            o[ct] = acc;
        }
    }

    // reduce l across the 32 key-lanes of each half-group
    #pragma unroll
    for (int r = 0; r < 16; ++r) {
        float l = l_part[r];
        l += __shfl_xor(l, 1);
        l += __shfl_xor(l, 2);
        l += __shfl_xor(l, 4);
        l += __shfl_xor(l, 8);
        l += __shfl_xor(l, 16);
        l_part[r] = l;
    }

    __syncthreads();                       // PV reads of Ps done -> alias Lp
    float* Lp = (float*)Ps;                // [2 kh][64 rows] partial sums
    if (l32 == 0) {
        #pragma unroll
        for (int r = 0; r < 16; ++r) {
            const int lrow = rh*32 + 4*half + (r & 3) + 8*(r >> 2);
            Lp[kh*64 + lrow] = l_part[r];
        }
    }
    __syncthreads();

    if (nsp == 1) {
        #pragma unroll
        for (int r = 0; r < 16; ++r) {
            const int lrow = rh*32 + 4*half + (r & 3) + 8*(r >> 2);
            const float inv = 1.0f / (Lp[lrow] + Lp[64 + lrow]);
            const int qgi = qt*64 + lrow;
            #pragma unroll
            for (int ct = 0; ct < 4; ++ct)
                Ret[((size_t)b*S_LEN + qgi)*HDIM + h*DIM + cw + ct*32 + l32]
                    = (bf16)(o[ct][r] * inv);
        }
    } else {
        const int slotbase = (qt <= 21) ? ((qt - 11)*2 + s) : (22 + (qt - 22)*3 + s);
        const size_t slot = (size_t)bh*52 + slotbase;
        bf16*  Ob = Opart + slot * (64*256);
        float* Lb = Lpart + slot * 64;
        if (tid < 64) Lb[tid] = Lp[tid] + Lp[64 + tid];
        #pragma unroll
        for (int r = 0; r < 16; ++r) {
            const int lrow = rh*32 + 4*half + (r & 3) + 8*(r >> 2);
            #pragma unroll
            for (int ct = 0; ct < 4; ++ct)
                Ob[(size_t)lrow*256 + cw + ct*32 + l32] = (bf16)o[ct][r];
        }
    }
}

// Sum the 2 or 3 partials of each split q-tile, normalize, write Ret.
// grid = 16 bh x 21 tiles = 336 blocks, 256 threads.
__global__ __launch_bounds__(256) void combine_kernel(const bf16* __restrict__ Opart,
                                                      const float* __restrict__ Lpart,
                                                      bf16* __restrict__ Ret)
{
    const int bx = blockIdx.x;
    const int bh = bx / 21;
    const int ti = bx - bh*21;
    const int qt = 11 + ti;
    const int n  = (qt <= 21) ? 2 : 3;
    const int slotbase = (qt <= 21) ? (qt - 11)*2 : (22 + (qt - 22)*3);
    const size_t slot0 = (size_t)bh*52 + slotbase;
    const int b = bh >> 3, h = bh & 7;
    const int row  = threadIdx.x >> 2;
    const int col0 = (threadIdx.x & 3) * 64;

    float l = 0.f;
    for (int i = 0; i < n; ++i) l += Lpart[(slot0 + i)*64 + row];
    const float inv = 1.0f / l;

    const bf16* O0 = Opart + slot0 * (64*256) + (size_t)row*256 + col0;
    const int q = qt*64 + row;
    bf16* dst = Ret + ((size_t)b*S_LEN + q)*HDIM + h*DIM + col0;
    #pragma unroll
    for (int ch = 0; ch < 8; ++ch) {
        float acc[8] = {};
        for (int i = 0; i < n; ++i) {
            bf16x8 a = *(const bf16x8*)(O0 + (size_t)i*(64*256) + ch*8);
            #pragma unroll
            for (int j = 0; j < 8; ++j) acc[j] += (float)a[j];
        }
        bf16x8 w;
        #pragma unroll
        for (int j = 0; j < 8; ++j) w[j] = (bf16)(acc[j] * inv);
        *(bf16x8*)(dst + ch*8) = w;
    }
}

// ---------------------------------------------------------------------------

extern "C" void kernel_launch(void* const* d_in, const int* in_sizes, int n_in,
                              void* d_out, int out_size, void* d_ws, size_t ws_size,
                              hipStream_t stream)
{
    (void)in_sizes; (void)n_in; (void)ws_size;
    const float* X  = (const float*)d_in[0];
    // d_in[1] timestamp, d_in[6] theta: dead code in reference output
    const float* wQ = (const float*)d_in[2];
    const float* wK = (const float*)d_in[3];
    const float* wV = (const float*)d_in[4];
    const float* wO = (const float*)d_in[5];

    char* ws = (char*)d_ws;
    const size_t MB = 1u << 20;
    bf16*  Xb    = (bf16*)(ws + 0*MB);    // [B,S,D]        2 MB
    bf16*  WQt   = (bf16*)(ws + 2*MB);    // [H,E,D]        1 MB
    bf16*  WKt   = (bf16*)(ws + 3*MB);
    bf16*  WVt   = (bf16*)(ws + 4*MB);
    bf16*  WOt   = (bf16*)(ws + 5*MB);    // [D,H*D]        1 MB
    bf16*  Qg    = (bf16*)(ws + 6*MB);    // [B,H,S,D]     16 MB
    bf16*  Kg    = (bf16*)(ws + 22*MB);   // [B,H,S,D]     16 MB
    bf16*  VTg   = (bf16*)(ws + 38*MB);   // [B,H,D,S]     16 MB
    bf16*  Ret   = (bf16*)(ws + 54*MB);   // [B,S,H*D]     16 MB
    bf16*  Opart = (bf16*)(ws + 70*MB);   // 832 slots x 64x256 bf16 = 27.25 MB
    float* Lpart = (float*)(ws + 98*MB);  // 832 x 64 fp32 = 208 KB

    hipMemsetAsync(d_out, 0, (size_t)out_size * sizeof(float), stream);

    prep_kernel    <<<dim3(4, 32, 5), 256, 0, stream>>>(X, wQ, wK, wV, wO,
                                                        Xb, WQt, WKt, WVt, WOt);
    proj_kernel    <<<dim3(32, 48), 256, 0, stream>>>(Xb, WQt, WKt, WVt, Qg, Kg, VTg);
    attn_kernel    <<<1008,         256, 0, stream>>>(Qg, Kg, VTg, Ret, Opart, Lpart);
    combine_kernel <<<336,          256, 0, stream>>>(Opart, Lpart, Ret);
    outproj_kernel <<<256,          256, 0, stream>>>(Ret, WOt, (float*)d_out);
}

// Round 14
// 184.475 us; speedup vs baseline: 1.2809x; 1.2809x over previous
//
#include <hip/hip_runtime.h>
#include <cstdint>
#include <cstddef>

// Problem constants (B,S,D,H) = (2, 2048, 256, 8)
#define S_LEN 2048
#define DIM   256
#define NH    8
#define NB    2
#define HDIM  (NH * DIM)   // 2048

using bf16 = __bf16;
typedef __bf16 bf16x8 __attribute__((ext_vector_type(8)));
typedef __bf16 bf16x4 __attribute__((ext_vector_type(4)));
typedef float  f32x4  __attribute__((ext_vector_type(4)));

typedef const __attribute__((address_space(1))) unsigned int* as1_u32p;
typedef __attribute__((address_space(3))) unsigned int* as3_u32p;

// async 16B global -> LDS (no VGPR round-trip). LDS dest = wave-uniform base
// + lane*16 (m104/m108).
__device__ __forceinline__ void cp16(const bf16* g, bf16* l) {
    __builtin_amdgcn_global_load_lds((as1_u32p)g, (as3_u32p)l, 16, 0, 0);
}

// ---------------------------------------------------------------------------
// Fused prep (one launch): z=0..2 -> wQ/wK/wV transpose-cast (h = y>>2),
// z=3 -> wO transpose-cast, z=4 -> X fp32->bf16 cast. grid dim3(4,32,5).
// ---------------------------------------------------------------------------
__global__ __launch_bounds__(256) void prep_kernel(const float* __restrict__ X,
                                                   const float* __restrict__ wQ,
                                                   const float* __restrict__ wK,
                                                   const float* __restrict__ wV,
                                                   const float* __restrict__ wO,
                                                   bf16* __restrict__ Xb,
                                                   bf16* __restrict__ WQt,
                                                   bf16* __restrict__ WKt,
                                                   bf16* __restrict__ WVt,
                                                   bf16* __restrict__ WOt)
{
    const int z = blockIdx.z;
    if (z == 4) {                     // cast X
        const int t = (blockIdx.y*4 + blockIdx.x)*256 + threadIdx.x;   // 0..32767
        #pragma unroll
        for (int p = 0; p < 8; ++p) {
            const int i = (t + p*32768)*4;
            float4 v = *(const float4*)(X + i);
            bf16x4 o;
            o[0] = (bf16)v.x; o[1] = (bf16)v.y; o[2] = (bf16)v.z; o[3] = (bf16)v.w;
            *(bf16x4*)(Xb + i) = o;
        }
        return;
    }
    __shared__ float tile[64][65];
    const float* in; bf16* out; int R, C, r0, c0;
    if (z < 3) {
        const int h = blockIdx.y >> 2;
        in  = (z == 0 ? wQ : z == 1 ? wK : wV) + (size_t)h * DIM * DIM;
        out = (z == 0 ? WQt : z == 1 ? WKt : WVt) + (size_t)h * DIM * DIM;
        R = DIM; C = DIM; r0 = (blockIdx.y & 3) * 64; c0 = blockIdx.x * 64;
    } else {
        in = wO; out = WOt; R = HDIM; C = DIM;
        r0 = blockIdx.y * 64; c0 = blockIdx.x * 64;
    }
    const int tr  = threadIdx.x >> 4;
    const int tc4 = (threadIdx.x & 15) * 4;
    #pragma unroll
    for (int p = 0; p < 4; ++p) {
        int row = p * 16 + tr;
        float4 v = *(const float4*)(in + (size_t)(r0 + row) * C + c0 + tc4);
        tile[row][tc4+0] = v.x; tile[row][tc4+1] = v.y;
        tile[row][tc4+2] = v.z; tile[row][tc4+3] = v.w;
    }
    __syncthreads();
    #pragma unroll
    for (int p = 0; p < 4; ++p) {
        int orow = p * 16 + tr;
        bf16x4 o;
        #pragma unroll
        for (int j = 0; j < 4; ++j) o[j] = (bf16)tile[tc4 + j][orow];
        *(bf16x4*)(out + (size_t)(c0 + orow) * R + r0 + tc4) = o;
    }
}

// ---------------------------------------------------------------------------
// 128x128-tile bf16 MFMA GEMM, ROUND-8-verified (async-DMA, XOR swizzle,
// single barrier per k-step). EPI: 0 bf16, 1 f32, 2 f32 atomicAdd.
// ---------------------------------------------------------------------------
template<int EPI>
__device__ __forceinline__ void gemm_tile(const bf16* __restrict__ A, const bf16* __restrict__ BT,
                                          void* __restrict__ C, bf16* As, bf16* Bs,
                                          int tm, int tn, int K, int lda, int ldb, int ldc)
{
    const int tid  = threadIdx.x;
    const int lane = tid & 63;
    const int wave = tid >> 6;
    const int wm   = (wave >> 1) << 6;
    const int wn   = (wave & 1) << 6;
    const int l16  = lane & 15;
    const int quad = lane >> 4;

    const int m0 = tm << 7, n0 = tn << 7;

    const int srow = (lane >> 2);
    const int gch  = (lane & 3) ^ (srow & 3);

    f32x4 acc[4][4] = {};

    const int ksteps = K >> 5;

    #pragma unroll
    for (int j = 0; j < 2; ++j) {
        const int g = wave*2 + j;
        cp16(A  + (size_t)(m0 + g*16 + srow)*lda + (gch << 3), As + g*512);
        cp16(BT + (size_t)(n0 + g*16 + srow)*ldb + (gch << 3), Bs + g*512);
    }

    for (int ks = 0; ks < ksteps; ++ks) {
        const int pb = ks & 1;
        asm volatile("s_waitcnt vmcnt(0)" ::: "memory");
        __syncthreads();
        if (ks + 1 < ksteps) {
            const int k1 = (ks + 1) << 5;
            #pragma unroll
            for (int j = 0; j < 2; ++j) {
                const int g = wave*2 + j;
                cp16(A  + (size_t)(m0 + g*16 + srow)*lda + k1 + (gch << 3),
                     As + (pb ^ 1)*4096 + g*512);
                cp16(BT + (size_t)(n0 + g*16 + srow)*ldb + k1 + (gch << 3),
                     Bs + (pb ^ 1)*4096 + g*512);
            }
        }
        const bf16* Ab = As + pb*4096;
        const bf16* Bb = Bs + pb*4096;
        bf16x8 af[4], bfv[4];
        #pragma unroll
        for (int i = 0; i < 4; ++i) {
            const int row = wm + i*16 + l16;
            af[i]  = *(const bf16x8*)(Ab + row*32 + ((quad ^ (l16 & 3)) << 3));
        }
        #pragma unroll
        for (int i = 0; i < 4; ++i) {
            const int row = wn + i*16 + l16;
            bfv[i] = *(const bf16x8*)(Bb + row*32 + ((quad ^ (l16 & 3)) << 3));
        }
        #pragma unroll
        for (int i = 0; i < 4; ++i)
            #pragma unroll
            for (int j = 0; j < 4; ++j)
                acc[i][j] = __builtin_amdgcn_mfma_f32_16x16x32_bf16(af[i], bfv[j], acc[i][j], 0, 0, 0);
    }

    #pragma unroll
    for (int i = 0; i < 4; ++i)
        #pragma unroll
        for (int j = 0; j < 4; ++j)
            #pragma unroll
            for (int r = 0; r < 4; ++r) {
                int mg = m0 + wm + i*16 + quad*4 + r;
                int ng = n0 + wn + j*16 + l16;
                float v = acc[i][j][r];
                if (EPI == 0)      ((bf16*)C)[(size_t)mg * ldc + ng] = (bf16)v;
                else if (EPI == 1) ((float*)C)[(size_t)mg * ldc + ng] = v;
                else               atomicAdd(&((float*)C)[(size_t)mg * ldc + ng], v);
            }
}

// QKV projections. grid = (32 tiles, 48 = {Q,K,V} x b x h). LDS 32 KB.
__global__ __launch_bounds__(256) void proj_kernel(const bf16* __restrict__ Xb,
    const bf16* __restrict__ WQt, const bf16* __restrict__ WKt, const bf16* __restrict__ WVt,
    bf16* __restrict__ Qg, bf16* __restrict__ Kg, bf16* __restrict__ VTg)
{
    __shared__ __align__(16) bf16 smem[4 * 4096];
    const int by  = blockIdx.y;
    const int mat = by >> 4;
    const int b   = (by >> 3) & 1;
    const int h   = by & 7;
    const int bx  = blockIdx.x;
    const bf16*  Xbb = Xb + (size_t)b * S_LEN * DIM;
    const size_t bh  = (size_t)(b * NH + h);
    if (mat == 0) {
        gemm_tile<0>(Xbb, WQt + (size_t)h*DIM*DIM, Qg + bh*S_LEN*DIM, smem, smem + 8192,
                     bx & 15, bx >> 4, DIM, DIM, DIM, DIM);
    } else if (mat == 1) {
        gemm_tile<0>(Xbb, WKt + (size_t)h*DIM*DIM, Kg + bh*S_LEN*DIM, smem, smem + 8192,
                     bx & 15, bx >> 4, DIM, DIM, DIM, DIM);
    } else {
        gemm_tile<0>(WVt + (size_t)h*DIM*DIM, Xbb, VTg + bh*DIM*S_LEN, smem, smem + 8192,
                     bx & 1, bx >> 1, DIM, DIM, DIM, S_LEN);
    }
}

// outproj to 4 fp32 slabs (no atomics): slab[kq][4096][256] = Ret@WOt k-slice.
__global__ __launch_bounds__(256) void outproj_kernel(const bf16* __restrict__ Ret,
                                                      const bf16* __restrict__ WOt,
                                                      float* __restrict__ slabs)
{
    __shared__ __align__(16) bf16 smem[4 * 4096];
    int bx = blockIdx.x;
    int t  = bx & 63;
    int kq = bx >> 6;
    gemm_tile<1>(Ret + kq*512, WOt + kq*512, slabs + (size_t)kq*4096*256,
                 smem, smem + 8192, t >> 1, t & 1, 512, HDIM, HDIM, DIM);
}

// sum 4 slabs -> d_out. 1024 blocks x 256 thr x float4.
__global__ __launch_bounds__(256) void reduce_out_kernel(const float* __restrict__ slabs,
                                                         float* __restrict__ out)
{
    const size_t i = ((size_t)blockIdx.x*256 + threadIdx.x)*4;
    const size_t N = (size_t)4096*256;
    float4 a = *(const float4*)(slabs + i);
    float4 b = *(const float4*)(slabs + N + i);
    float4 c = *(const float4*)(slabs + 2*N + i);
    float4 d = *(const float4*)(slabs + 3*N + i);
    float4 w;
    w.x = a.x + b.x + c.x + d.x;
    w.y = a.y + b.y + c.y + d.y;
    w.z = a.z + b.z + c.z + d.z;
    w.w = a.w + b.w + c.w + d.w;
    *(float4*)(out + i) = w;
}

// ---------------------------------------------------------------------------
// Split-K flash causal attention (round 14): 64-key steps, all layouts and
// sub-patterns HW-verified (16x16x32 MFMA, R10 col-split PV, R13 barrier/DMA
// schedule, R7 XOR swizzles, R12 uniform partition). Theory: the ~70us
// plateau is sync-events-per-key (4 barriers + 4 DMA waits / 64 keys);
// this kernel has 2 barriers + 1 explicit wait per 64 keys.
// Per step: (A) raw barrier -> issue V(t) -> (B) vmcnt(8) K-wait -> QK ->
// softmax/Ps -> (C) __syncthreads -> issue K(t+1) -> PV (col-split).
// LDS: K 32K + V 32K + Ps 9K = 74752 B -> 2 blocks/CU. ~130 VGPR, no spill.
// ---------------------------------------------------------------------------
__global__ __launch_bounds__(256, 2) void attn_kernel(const bf16* __restrict__ Qg,
                                                      const bf16* __restrict__ Kg,
                                                      const bf16* __restrict__ VTg,
                                                      bf16* __restrict__ Ret,
                                                      bf16* __restrict__ Opart,
                                                      float* __restrict__ Lpart)
{
    __shared__ __align__(16) bf16 Ks [64 * 256];   // 32 KB, swizzle c^(row&31)
    __shared__ __align__(16) bf16 VTs[256 * 64];   // 32 KB, swizzle c^(e&7)
    __shared__ __align__(16) bf16 Ps [64 * 72];    // 9 KB, padded

    // dispatch-slot -> bid, sorted by 64-key block length descending (R13)
    static const unsigned char order[63] = {
        10,29,31,32,57,60,61,
        9,25,27,28,30,48,51,52,54,55,56,58,59,62,
        8,21,23,24,26,39,42,43,45,46,47,49,50,53,
        7,17,19,20,22,33,34,36,37,38,40,41,44,
        6,13,15,16,18,35,
        5,11,12,14,
        4,3,2,1,0 };

    const int tid  = threadIdx.x;
    const int lane = tid & 63;
    const int wave = tid >> 6;
    const int l16  = lane & 15;
    const int quad = lane >> 4;
    const int cw   = wave << 6;            // PV col strip

    // ---- uniform-length work mapping (R12/R13) ----
    const int bx  = blockIdx.x;                      // 0..1007
    const int bh  = bx & 15;
    const int bid = order[bx >> 4];                  // 0..62
    int qt, s, nsp;
    if (bid <= 10)      { qt = bid;                    s = 0;       nsp = 1; }
    else if (bid <= 32) { int k = bid - 11; qt = 11 + (k >> 1); s = k & 1; nsp = 2; }
    else                { int k = bid - 33; int q3 = k / 3; qt = 22 + q3; s = k - 3*q3; nsp = 3; }
    const int b = bh >> 3, h = bh & 7;

    const int S2 = qt + 1;                 // total 64-key steps
    const int base = S2 / nsp, rem = S2 - nsp*base;
    const int kstep0 = s*base + (s < rem ? s : rem);
    const int kstep1 = kstep0 + base + (s < rem ? 1 : 0);

    const bf16* Qbh  = Qg  + (size_t)(b*NH + h) * S_LEN * DIM;
    const bf16* Kbh  = Kg  + (size_t)(b*NH + h) * S_LEN * DIM;
    const bf16* VTbh = VTg + (size_t)(b*NH + h) * DIM * S_LEN;

    const int qbase = qt*64 + wave*16;     // QK: this wave's 16 rows

    // Preload this wave's 16 Q rows as 8 A-frags (full D=256)
    bf16x8 qf[8];
    #pragma unroll
    for (int kc = 0; kc < 8; ++kc)
        qf[kc] = *(const bf16x8*)(Qbh + (size_t)(qbase + l16)*DIM + kc*32 + quad*8);

    f32x4 o[16] = {};                      // [rt*4+ct]: 64 rows x 64 cols (strip)
    float l_part[4] = {0.f, 0.f, 0.f, 0.f};

    // prologue: issue K(kstep0) (64x256 = 2048 chunks, 8 cp16/wave)
    {
        const int t00 = kstep0 << 6;
        #pragma unroll
        for (int j = 0; j < 8; ++j) {
            const int sN = ((wave*8 + j) << 6) + lane;
            const int ts = sN >> 5, cs = sN & 31;
            cp16(Kbh + (size_t)(t00 + ts)*DIM + ((cs ^ (ts & 31)) << 3),
                 Ks + ((wave*8 + j) << 9));
        }
    }

    for (int step = kstep0; step < kstep1; ++step) {
        const int t0 = step << 6;
        // (A) prev PV reads of VTs/Ps complete (raw barrier: keep K in flight)
        asm volatile("s_barrier" ::: "memory");
        // issue V(t): 256x64 = 2048 chunks, 8 cp16/wave
        #pragma unroll
        for (int j = 0; j < 8; ++j) {
            const int sN = ((wave*8 + j) << 6) + lane;
            const int es = sN >> 3, cs = sN & 7;
            cp16(VTbh + (size_t)es*S_LEN + t0 + ((cs ^ (es & 7)) << 3),
                 VTs + ((wave*8 + j) << 9));
        }
        // (B) wait K(t) only (8 newest = V stay outstanding); align waves
        asm volatile("s_waitcnt vmcnt(8)\n\ts_barrier" ::: "memory");

        // QK: S = Q K^T, 16 rows x 64 keys (4 key-tiles), XOR-swizzled K
        f32x4 sacc[4] = {};
        #pragma unroll
        for (int kc = 0; kc < 8; ++kc) {
            const int ch = (kc << 2) + quad;
            #pragma unroll
            for (int kt = 0; kt < 4; ++kt) {
                const int row = kt*16 + l16;
                bf16x8 kf = *(const bf16x8*)(Ks + row*256 + ((ch ^ (row & 31)) << 3));
                sacc[kt] = __builtin_amdgcn_mfma_f32_16x16x32_bf16(qf[kc], kf, sacc[kt], 0,0,0);
            }
        }

        // softmax (no-max): p = exp(s/16) masked; row-sums; write P to Ps
        #pragma unroll
        for (int kt = 0; kt < 4; ++kt) {
            const int tg = t0 + kt*16 + l16;
            #pragma unroll
            for (int r = 0; r < 4; ++r) {
                const int qgi = qbase + quad*4 + r;
                float p = (tg <= qgi) ? __expf(sacc[kt][r] * 0.0625f) : 0.0f;
                l_part[r] += p;
                Ps[(wave*16 + quad*4 + r)*72 + kt*16 + l16] = (bf16)p;
            }
        }
        // (C) Ps visible; all QK reads of Ks done; V(t) drained (needed next)
        __syncthreads();

        // issue K(t+1) into Ks (safe: PV never reads Ks)
        if (step + 1 < kstep1) {
            const int t1 = (step + 1) << 6;
            #pragma unroll
            for (int j = 0; j < 8; ++j) {
                const int sN = ((wave*8 + j) << 6) + lane;
                const int ts = sN >> 5, cs = sN & 31;
                cp16(Kbh + (size_t)(t1 + ts)*DIM + ((cs ^ (ts & 31)) << 3),
                     Ks + ((wave*8 + j) << 9));
            }
        }

        // PV col-split: ALL 64 rows x this wave's 64-col strip; K-contraction
        // 64 keys = 2 MFMA k-chunks of 32.
        #pragma unroll
        for (int kc2 = 0; kc2 < 2; ++kc2) {
            bf16x8 pf[4];
            #pragma unroll
            for (int rt = 0; rt < 4; ++rt)
                pf[rt] = *(const bf16x8*)(Ps + (rt*16 + l16)*72 + kc2*32 + quad*8);
            #pragma unroll
            for (int ct = 0; ct < 4; ++ct) {
                const int e = cw + ct*16 + l16;
                const int g = (kc2 << 2) + quad;
                bf16x8 vf = *(const bf16x8*)(VTs + e*64 + ((g ^ (e & 7)) << 3));
                #pragma unroll
                for (int rt = 0; rt < 4; ++rt)
                    o[rt*4 + ct] = __builtin_amdgcn_mfma_f32_16x16x32_bf16(pf[rt], vf, o[rt*4 + ct], 0,0,0);
            }
        }
    }

    // row-sum reduction across the 16 key-lanes (this wave's 16 QK rows)
    float lsum[4];
    #pragma unroll
    for (int r = 0; r < 4; ++r) {
        float l = l_part[r];
        l += __shfl_xor(l, 1);
        l += __shfl_xor(l, 2);
        l += __shfl_xor(l, 4);
        l += __shfl_xor(l, 8);
        lsum[r] = l;
    }

    // broadcast all 64 row-sums via LDS (alias into Ps after PV reads done)
    __syncthreads();
    float* Lp = (float*)Ps;
    if (l16 == 0) {
        #pragma unroll
        for (int r = 0; r < 4; ++r) Lp[wave*16 + quad*4 + r] = lsum[r];
    }
    __syncthreads();

    if (nsp == 1) {
        #pragma unroll
        for (int rt = 0; rt < 4; ++rt)
            #pragma unroll
            for (int r = 0; r < 4; ++r) {
                const int row = rt*16 + quad*4 + r;
                const float inv = 1.0f / Lp[row];
                #pragma unroll
                for (int ct = 0; ct < 4; ++ct)
                    Ret[((size_t)b*S_LEN + qt*64 + row)*HDIM + h*DIM + cw + ct*16 + l16]
                        = (bf16)(o[rt*4 + ct][r] * inv);
            }
    } else {
        const int slotbase = (qt <= 21) ? ((qt - 11)*2 + s) : (22 + (qt - 22)*3 + s);
        const size_t slot = (size_t)bh*52 + slotbase;
        bf16*  Ob = Opart + slot * (64*256);
        float* Lb = Lpart + slot * 64;
        if (l16 == 0) {
            #pragma unroll
            for (int r = 0; r < 4; ++r) Lb[wave*16 + quad*4 + r] = lsum[r];
        }
        #pragma unroll
        for (int rt = 0; rt < 4; ++rt)
            #pragma unroll
            for (int r = 0; r < 4; ++r) {
                const int row = rt*16 + quad*4 + r;
                #pragma unroll
                for (int ct = 0; ct < 4; ++ct)
                    Ob[(size_t)row*256 + cw + ct*16 + l16] = (bf16)o[rt*4 + ct][r];
            }
    }
}

// Sum the 2 or 3 partials of each split q-tile, normalize, write Ret.
// grid = 16 bh x 21 tiles = 336 blocks, 256 threads.
__global__ __launch_bounds__(256) void combine_kernel(const bf16* __restrict__ Opart,
                                                      const float* __restrict__ Lpart,
                                                      bf16* __restrict__ Ret)
{
    const int bx = blockIdx.x;
    const int bh = bx / 21;
    const int ti = bx - bh*21;
    const int qt = 11 + ti;
    const int n  = (qt <= 21) ? 2 : 3;
    const int slotbase = (qt <= 21) ? (qt - 11)*2 : (22 + (qt - 22)*3);
    const size_t slot0 = (size_t)bh*52 + slotbase;
    const int b = bh >> 3, h = bh & 7;
    const int row  = threadIdx.x >> 2;
    const int col0 = (threadIdx.x & 3) * 64;

    float l = 0.f;
    for (int i = 0; i < n; ++i) l += Lpart[(slot0 + i)*64 + row];
    const float inv = 1.0f / l;

    const bf16* O0 = Opart + slot0 * (64*256) + (size_t)row*256 + col0;
    const int q = qt*64 + row;
    bf16* dst = Ret + ((size_t)b*S_LEN + q)*HDIM + h*DIM + col0;
    #pragma unroll
    for (int ch = 0; ch < 8; ++ch) {
        float acc[8] = {};
        for (int i = 0; i < n; ++i) {
            bf16x8 a = *(const bf16x8*)(O0 + (size_t)i*(64*256) + ch*8);
            #pragma unroll
            for (int j = 0; j < 8; ++j) acc[j] += (float)a[j];
        }
        bf16x8 w;
        #pragma unroll
        for (int j = 0; j < 8; ++j) w[j] = (bf16)(acc[j] * inv);
        *(bf16x8*)(dst + ch*8) = w;
    }
}

// ---------------------------------------------------------------------------

extern "C" void kernel_launch(void* const* d_in, const int* in_sizes, int n_in,
                              void* d_out, int out_size, void* d_ws, size_t ws_size,
                              hipStream_t stream)
{
    (void)in_sizes; (void)n_in; (void)out_size; (void)ws_size;
    const float* X  = (const float*)d_in[0];
    // d_in[1] timestamp, d_in[6] theta: dead code in reference output
    const float* wQ = (const float*)d_in[2];
    const float* wK = (const float*)d_in[3];
    const float* wV = (const float*)d_in[4];
    const float* wO = (const float*)d_in[5];

    char* ws = (char*)d_ws;
    const size_t MB = 1u << 20;
    bf16*  Xb    = (bf16*)(ws + 0*MB);    // [B,S,D]        2 MB
    bf16*  WQt   = (bf16*)(ws + 2*MB);    // [H,E,D]        1 MB
    bf16*  WKt   = (bf16*)(ws + 3*MB);
    bf16*  WVt   = (bf16*)(ws + 4*MB);
    bf16*  WOt   = (bf16*)(ws + 5*MB);    // [D,H*D]        1 MB
    bf16*  Qg    = (bf16*)(ws + 6*MB);    // [B,H,S,D]     16 MB (dead after attn)
    bf16*  Kg    = (bf16*)(ws + 22*MB);   // [B,H,S,D]     16 MB
    bf16*  VTg   = (bf16*)(ws + 38*MB);   // [B,H,D,S]     16 MB
    bf16*  Ret   = (bf16*)(ws + 54*MB);   // [B,S,H*D]     16 MB
    bf16*  Opart = (bf16*)(ws + 70*MB);   // 832 slots x 64x256 bf16 = 27.25 MB
    float* Lpart = (float*)(ws + 98*MB);  // 832 x 64 fp32 = 208 KB
    float* slabs = (float*)Qg;            // reuse dead Qg: 4 x 4 MB fp32 = 16 MB

    prep_kernel    <<<dim3(4, 32, 5), 256, 0, stream>>>(X, wQ, wK, wV, wO,
                                                        Xb, WQt, WKt, WVt, WOt);
    proj_kernel    <<<dim3(32, 48), 256, 0, stream>>>(Xb, WQt, WKt, WVt, Qg, Kg, VTg);
    attn_kernel    <<<1008,         256, 0, stream>>>(Qg, Kg, VTg, Ret, Opart, Lpart);
    combine_kernel <<<336,          256, 0, stream>>>(Opart, Lpart, Ret);
    outproj_kernel <<<256,          256, 0, stream>>>(Ret, WOt, slabs);
    reduce_out_kernel<<<1024,       256, 0, stream>>>(slabs, (float*)d_out);
}